// Round 11
// baseline (270.834 us; speedup 1.0000x reference)
//
#include <hip/hip_runtime.h>
#include <hip/hip_bf16.h>
#include <cstdint>

// Problem constants
#define BB 4
#define SS 4096
#define DD 1024
#define MM (BB * SS)          // 16384 tokens
#define NTOT 4096             // 4 matrices * 1024 output features
#define BUDGET 2048

typedef __attribute__((ext_vector_type(8))) short short8v;   // 8 bf16 (4 VGPR)
typedef __attribute__((ext_vector_type(4))) float f32x4;

__device__ __forceinline__ float bf2f(unsigned int h) {
  return __uint_as_float(h << 16);
}
__device__ __forceinline__ unsigned short f2bf(float f) {
  unsigned int u = __float_as_uint(f);
  u = u + 0x7FFFu + ((u >> 16) & 1u);   // RNE
  return (unsigned short)(u >> 16);
}
__device__ __forceinline__ unsigned int pkbf(float lo, float hi) {
  float2 f; f.x = lo; f.y = hi;
  __hip_bfloat162 h = __float22bfloat162_rn(f);
  return *(unsigned int*)&h;
}

// ---------------- convert2: bf16 copies of x & W-concat + fused codebook probs ----
// x-blocks stage Wc (64KB f32) in LDS once per block: kills the per-wave 64KB
// L2 re-read (1 GB aggregate -> ~30 MB HBM + LDS reads).
__global__ __launch_bounds__(256) void convert2_kernel(
    const float* __restrict__ x,
    const float* __restrict__ Wq, const float* __restrict__ Wk,
    const float* __restrict__ Wg, const float* __restrict__ Wm,
    const float* __restrict__ Wc,
    unsigned short* __restrict__ xb, unsigned short* __restrict__ Wb,
    float* __restrict__ probs)
{
  __shared__ float wcs[16 * 1024];   // 64 KB
  const int blk = blockIdx.x;
  const int t = threadIdx.x;
  if (blk < 4096) {
    // stage Wc: 4096 float4, 256 threads x 16
    #pragma unroll
    for (int i = 0; i < 16; ++i) {
      const int idx = i * 256 + t;
      ((float4*)wcs)[idx] = ((const float4*)Wc)[idx];
    }
    __syncthreads();

    const int wv = t >> 6, ln = t & 63;
    const int token = blk * 4 + wv;
    const size_t rowo = (size_t)token * DD;
    const float4* x4 = (const float4*)(x + rowo);
    const float4* Wc4 = (const float4*)wcs;
    float4 xv[4];
    #pragma unroll
    for (int e = 0; e < 4; ++e) xv[e] = x4[e * 64 + ln];
    uint2* xo = (uint2*)(xb + rowo);
    #pragma unroll
    for (int e = 0; e < 4; ++e) {
      uint2 o; o.x = pkbf(xv[e].x, xv[e].y); o.y = pkbf(xv[e].z, xv[e].w);
      xo[e * 64 + ln] = o;
    }
    float pj[16];
    #pragma unroll
    for (int j = 0; j < 16; ++j) {
      float a = 0.f;
      #pragma unroll
      for (int e = 0; e < 4; ++e) {
        const float4 w = Wc4[j * 256 + e * 64 + ln];
        a += xv[e].x * w.x + xv[e].y * w.y + xv[e].z * w.z + xv[e].w * w.w;
      }
      pj[j] = a;
    }
    #pragma unroll
    for (int j = 0; j < 16; ++j) {
      #pragma unroll
      for (int off = 1; off < 64; off <<= 1) pj[j] += __shfl_xor(pj[j], off);
    }
    if (ln == 0) {
      float p[16];
      float mx = -3.4e38f;
      #pragma unroll
      for (int j = 0; j < 16; ++j) { p[j] = pj[j] * 10.0f; mx = fmaxf(mx, p[j]); }
      float se = 0.f;
      #pragma unroll
      for (int j = 0; j < 16; ++j) { p[j] = expf(p[j] - mx); se += p[j]; }
      const float inv = 1.0f / se;
      #pragma unroll
      for (int j = 0; j < 16; ++j) p[j] *= inv;
      unsigned int mk = 0;
      for (int it = 0; it < 4; ++it) {
        int bi = 0; float bv = -1.f;
        #pragma unroll
        for (int j = 0; j < 16; ++j)
          if (!((mk >> j) & 1u) && p[j] > bv) { bv = p[j]; bi = j; }
        mk |= 1u << bi;
      }
      float ssum = 0.f;
      #pragma unroll
      for (int j = 0; j < 16; ++j) if ((mk >> j) & 1u) ssum += p[j];
      const float rinv = 1.0f / fmaxf(ssum, 1e-8f);
      #pragma unroll
      for (int j = 0; j < 16; ++j)
        probs[(size_t)token * 16 + j] = ((mk >> j) & 1u) ? p[j] * rinv : 0.f;
    }
  } else {
    const size_t off0 = (size_t)(blk - 4096) * 2048 + t * 8;
    const int m = (int)(off0 >> 20);
    const float* Ws = (m == 0) ? Wq : (m == 1) ? Wk : (m == 2) ? Wg : Wm;
    const size_t wo = off0 & 1048575u;
    const float4 a0 = *(const float4*)(Ws + wo);
    const float4 a1 = *(const float4*)(Ws + wo + 4);
    uint4 o;
    o.x = pkbf(a0.x, a0.y); o.y = pkbf(a0.z, a0.w);
    o.z = pkbf(a1.x, a1.y); o.w = pkbf(a1.z, a1.w);
    *(uint4*)(Wb + off0) = o;
  }
}

// ---------------- 256x256 MFMA GEMM, 16 waves (4Mx4N), BK=64 ----------------
// PROVEN round-10 version (145 us, 948 TF, SQ_LDS_BANK_CONFLICT=0).
// Pure-DMA double-buffered staging + counted vmcnt(4) + raw barriers;
// both-sides XOR swizzle ch=(s&7)^(row&7). UNCHANGED this round.
__global__ __launch_bounds__(1024, 4) void gemm256_kernel(
    const unsigned short* __restrict__ xb, const unsigned short* __restrict__ Wb,
    const float* __restrict__ bg, const float* __restrict__ bm,
    unsigned short* __restrict__ qb, unsigned short* __restrict__ kb,
    unsigned short* __restrict__ gb, unsigned short* __restrict__ mb)
{
  __shared__ __align__(16) unsigned short lds[65536];  // 128 KB: [2][A|B][256][64]
  const int t  = threadIdx.x;            // 0..1023
  const int wv = t >> 6, ln = t & 63;    // 16 waves
  const int wr = wv >> 2, wc = wv & 3;   // 4 (M) x 4 (N)
  const int frow = ln & 15, kc = ln >> 4;

  // bijective XCD swizzle: nwg = 1024, 8 XCDs, 128 blocks per chunk
  const int o  = blockIdx.y * 16 + blockIdx.x;
  const int L  = (o & 7) * 128 + (o >> 3);
  const int bx = L & 15, by = L >> 4;
  const int m0 = by * 256;
  const int n0 = bx * 256;
  const int mat = n0 >> 10;
  const int nc0 = n0 & 1023;

  f32x4 acc[4][4];
  #pragma unroll
  for (int i = 0; i < 4; ++i)
    #pragma unroll
    for (int j = 0; j < 4; ++j) { acc[i][j][0]=0.f; acc[i][j][1]=0.f; acc[i][j][2]=0.f; acc[i][j][3]=0.f; }

  auto stage = [&](int buf, int kt) {
    const int k0 = kt << 6;
    #pragma unroll
    for (int i = 0; i < 2; ++i) {
      const int s   = i * 1024 + t;        // 0..2047 (16B slots)
      const int row = s >> 3;              // 0..255
      const int ch  = (s & 7) ^ (row & 7); // both-sides swizzle
      const unsigned short* ga = xb + (size_t)(m0 + row) * DD + k0 + ch * 8;
      const unsigned short* gw = Wb + (size_t)(n0 + row) * DD + k0 + ch * 8;
      __builtin_amdgcn_global_load_lds(
          (const __attribute__((address_space(1))) void*)ga,
          (__attribute__((address_space(3))) void*)((__attribute__((address_space(3))) char*)lds
              + buf * 65536 + s * 16),
          16, 0, 0);
      __builtin_amdgcn_global_load_lds(
          (const __attribute__((address_space(1))) void*)gw,
          (__attribute__((address_space(3))) void*)((__attribute__((address_space(3))) char*)lds
              + buf * 65536 + 32768 + s * 16),
          16, 0, 0);
    }
  };

  stage(0, 0);   // 4 outstanding

  for (int kt = 0; kt < 16; ++kt) {
    const int cur = kt & 1;
    if (kt < 15) {
      stage(cur ^ 1, kt + 1);                              // 8 outstanding
      asm volatile("s_waitcnt vmcnt(4)" ::: "memory");     // tile kt's 4 done
    } else {
      asm volatile("s_waitcnt vmcnt(0)" ::: "memory");
    }
    __builtin_amdgcn_s_barrier();                          // tile kt fully in LDS
    asm volatile("" ::: "memory");

    #pragma unroll
    for (int kk = 0; kk < 2; ++kk) {
      const int sl = ((kk * 4 + kc) ^ (frow & 7)) << 3;    // swizzled read slot (ushorts)
      short8v a[4], b[4];
      #pragma unroll
      for (int i = 0; i < 4; ++i)
        a[i] = *(const short8v*)&lds[cur * 32768 + (wr * 64 + i * 16 + frow) * 64 + sl];
      #pragma unroll
      for (int j = 0; j < 4; ++j)
        b[j] = *(const short8v*)&lds[cur * 32768 + 16384 + (wc * 64 + j * 16 + frow) * 64 + sl];
      #pragma unroll
      for (int i = 0; i < 4; ++i)
        #pragma unroll
        for (int j = 0; j < 4; ++j)
          acc[i][j] = __builtin_amdgcn_mfma_f32_16x16x32_bf16(a[i], b[j], acc[i][j], 0, 0, 0);
    }

    asm volatile("" ::: "memory");                         // pin ds_reads above
    __builtin_amdgcn_s_barrier();                          // done reading buf[cur]
  }

  unsigned short* outp = (mat == 0) ? qb : (mat == 1) ? kb : (mat == 2) ? gb : mb;
  #pragma unroll
  for (int i = 0; i < 4; ++i) {
    #pragma unroll
    for (int j = 0; j < 4; ++j) {
      const int col = nc0 + wc * 64 + j * 16 + frow;
      const float bias = (mat == 2) ? bg[col] : (mat == 3) ? bm[col] : 0.f;
      #pragma unroll
      for (int r = 0; r < 4; ++r) {
        const int row = m0 + wr * 64 + i * 16 + kc * 4 + r;
        float v = acc[i][j][r] + bias;
        if (mat == 3) v = fmaxf(v, 0.0f);
        outp[(size_t)row * DD + col] = f2bf(v);
      }
    }
  }
}

// ---------------- fallback GEMM (ws too small): reg-staged f32->bf16, 128x128 ----
__global__ __launch_bounds__(256) void mfma_gemm_fb(
    const float* __restrict__ x,
    const float* __restrict__ Wq, const float* __restrict__ Wk,
    const float* __restrict__ Wg, const float* __restrict__ Wm,
    const float* __restrict__ bg, const float* __restrict__ bm,
    unsigned short* __restrict__ q_o, unsigned short* __restrict__ k_o,
    unsigned short* __restrict__ g_o, unsigned short* __restrict__ m_o)
{
  __shared__ __align__(16) unsigned short As[128 * 32];
  __shared__ __align__(16) unsigned short Bs[128 * 32];
  const int t  = threadIdx.x;
  const int wv = t >> 6, ln = t & 63;
  const int wr = wv >> 1, wc = wv & 1;
  const int m0 = blockIdx.y * 128;
  const int n0 = blockIdx.x * 128;
  const int mat = n0 >> 10;
  const int nc0 = n0 & 1023;
  const float* __restrict__ Wsrc = (mat == 0) ? Wq : (mat == 1) ? Wk : (mat == 2) ? Wg : Wm;

  f32x4 acc[4][4];
  #pragma unroll
  for (int i = 0; i < 4; ++i)
    #pragma unroll
    for (int j = 0; j < 4; ++j) { acc[i][j][0]=0.f; acc[i][j][1]=0.f; acc[i][j][2]=0.f; acc[i][j][3]=0.f; }

  const int frow = ln & 15, kc = ln >> 4;

  for (int k0 = 0; k0 < DD; k0 += 32) {
    #pragma unroll
    for (int c = 0; c < 2; ++c) {
      const int i = c * 256 + t;
      const int row = i >> 2, colc = i & 3;
      const float* ga = x    + (size_t)(m0 + row) * DD + k0 + (colc << 3);
      const float* gw = Wsrc + (size_t)(nc0 + row) * DD + k0 + (colc << 3);
      const float4 a0 = *(const float4*)ga, a1 = *(const float4*)(ga + 4);
      const float4 b0 = *(const float4*)gw, b1 = *(const float4*)(gw + 4);
      uint4 ao, bo;
      ao.x = pkbf(a0.x, a0.y); ao.y = pkbf(a0.z, a0.w);
      ao.z = pkbf(a1.x, a1.y); ao.w = pkbf(a1.z, a1.w);
      bo.x = pkbf(b0.x, b0.y); bo.y = pkbf(b0.z, b0.w);
      bo.z = pkbf(b1.x, b1.y); bo.w = pkbf(b1.z, b1.w);
      *(uint4*)&As[row * 32 + colc * 8] = ao;
      *(uint4*)&Bs[row * 32 + colc * 8] = bo;
    }
    __syncthreads();
    short8v a[4], b[4];
    #pragma unroll
    for (int i = 0; i < 4; ++i) {
      a[i] = *(const short8v*)&As[(wr * 64 + i * 16 + frow) * 32 + kc * 8];
      b[i] = *(const short8v*)&Bs[(wc * 64 + i * 16 + frow) * 32 + kc * 8];
    }
    #pragma unroll
    for (int i = 0; i < 4; ++i)
      #pragma unroll
      for (int j = 0; j < 4; ++j)
        acc[i][j] = __builtin_amdgcn_mfma_f32_16x16x32_bf16(a[i], b[j], acc[i][j], 0, 0, 0);
    __syncthreads();
  }

  unsigned short* outp = (mat == 0) ? q_o : (mat == 1) ? k_o : (mat == 2) ? g_o : m_o;
  #pragma unroll
  for (int i = 0; i < 4; ++i) {
    #pragma unroll
    for (int j = 0; j < 4; ++j) {
      const int col = nc0 + wc * 64 + j * 16 + frow;
      #pragma unroll
      for (int r = 0; r < 4; ++r) {
        const int row = m0 + wr * 64 + i * 16 + kc * 4 + r;
        float v = acc[i][j][r];
        if (mat == 2) v += bg[col];
        if (mat == 3) v = fmaxf(v + bm[col], 0.0f);
        outp[(size_t)row * DD + col] = f2bf(v);
      }
    }
  }
}

// ---------------- Phase 2 (slim): wave-per-token gate/topk/twist ----------------
// NEW: block-cooperative LDS staging of the 5 shared q-rows + 5 k-rows
// (tokens T0-1..T0+3) -> q/k global loads drop 8+8 -> 5+5 rows per block.
// Staging + __syncthreads happen BEFORE the s==0 early-out (no barrier
// divergence). Row T0-1 is clamped to T0 at batch starts (value unused there).
// Selection logic (g keys, search, tie-break) untouched.
__global__ __launch_bounds__(256) void token_kernel3(
    const unsigned short* __restrict__ qb, const unsigned short* __restrict__ kb,
    const unsigned short* __restrict__ gb, const unsigned short* __restrict__ mb,
    float* __restrict__ craw)
{
  __shared__ __align__(16) unsigned short qsh[5][1024];
  __shared__ __align__(16) unsigned short ksh[5][1024];
  const int t = threadIdx.x;
  const int wv = t >> 6;
  const int ln = t & 63;
  const int T0 = blockIdx.x * 4;
  const bool batch_start = ((T0 & (SS - 1)) == 0);

  // cooperative stage: 10 rows x 128 uint4 = 1280 uint4; 256 threads x 5
  #pragma unroll
  for (int i = 0; i < 5; ++i) {
    const int li  = i * 256 + t;          // 0..1279
    const int row = li >> 7;              // 0..9 (0..4 = q, 5..9 = k)
    const int col = (li & 127) * 8;       // ushort offset within row
    const int rr  = (row < 5) ? row : row - 5;
    const int tok = (batch_start && rr == 0) ? T0 : (T0 - 1 + rr);
    const unsigned short* src = (row < 5) ? qb : kb;
    unsigned short* dst = (row < 5) ? &qsh[row][0] : &ksh[row - 5][0];
    *(uint4*)(dst + col) = *(const uint4*)(src + (size_t)tok * DD + col);
  }
  __syncthreads();

  const int token = T0 + wv;
  const int s = token & (SS - 1);
  const size_t rowo = (size_t)token * DD;

  if (s == 0) { if (ln == 0) craw[token] = 0.f; return; }

  unsigned short gbit[16];
  *(uint4*)&gbit[0] = *(const uint4*)(gb + rowo + ln * 16);
  *(uint4*)&gbit[8] = *(const uint4*)(gb + rowo + ln * 16 + 8);
  int ckey[16];
  float asum = 0.f;
  #pragma unroll
  for (int i = 0; i < 16; ++i) {
    const unsigned int b = gbit[i];
    ckey[i] = (b & 0x8000u) ? (int)(b ^ 0xFFFFu) : (int)(b | 0x8000u);
    asum += bf2f(b & 0x7FFFu);
  }
  #pragma unroll
  for (int off = 1; off < 64; off <<= 1) asum += __shfl_xor(asum, off);
  const float strength = tanhf(asum * (1.0f / 1024.0f));
  int kkv = (int)ceilf(strength * 256.0f);
  kkv = min(max(kkv, 1), 1024);

  int lo = 0, hi = 0xFFFF;
  while (lo < hi) {
    const int mid = (lo + hi + 1) >> 1;
    int c = 0;
    #pragma unroll
    for (int i = 0; i < 16; ++i) c += (ckey[i] >= mid);
    #pragma unroll
    for (int off = 1; off < 64; off <<= 1) c += __shfl_xor(c, off);
    if (c >= kkv) lo = mid; else hi = mid - 1;
  }
  const int T = lo;

  int cg = 0, myeq = 0;
  #pragma unroll
  for (int i = 0; i < 16; ++i) { cg += (ckey[i] > T); myeq += (ckey[i] == T); }
  #pragma unroll
  for (int off = 1; off < 64; off <<= 1) cg += __shfl_xor(cg, off);
  int incl = myeq;
  #pragma unroll
  for (int off = 1; off < 64; off <<= 1) {
    const int tt = __shfl_up(incl, off);
    if (ln >= off) incl += tt;
  }
  int ebase = incl - myeq;
  const int keep_eq = kkv - cg;

  unsigned short mB[16], qcB[16], kcB[16], qpB[16], kpB[16];
  *(uint4*)&mB[0]  = *(const uint4*)(mb + rowo + ln * 16);
  *(uint4*)&mB[8]  = *(const uint4*)(mb + rowo + ln * 16 + 8);
  *(uint4*)&qcB[0] = *(const uint4*)(&qsh[wv + 1][ln * 16]);
  *(uint4*)&qcB[8] = *(const uint4*)(&qsh[wv + 1][ln * 16 + 8]);
  *(uint4*)&kcB[0] = *(const uint4*)(&ksh[wv + 1][ln * 16]);
  *(uint4*)&kcB[8] = *(const uint4*)(&ksh[wv + 1][ln * 16 + 8]);
  *(uint4*)&qpB[0] = *(const uint4*)(&qsh[wv][ln * 16]);
  *(uint4*)&qpB[8] = *(const uint4*)(&qsh[wv][ln * 16 + 8]);
  *(uint4*)&kpB[0] = *(const uint4*)(&ksh[wv][ln * 16]);
  *(uint4*)&kpB[8] = *(const uint4*)(&ksh[wv][ln * 16 + 8]);

  float accv = 0.f;
  #pragma unroll
  for (int i = 0; i < 16; ++i) {
    const bool kp_ = (ckey[i] > T) || (ckey[i] == T && ebase < keep_eq);
    if (ckey[i] == T) ebase++;
    const unsigned int b = gbit[i];
    const bool gpos = (!(b & 0x8000u)) && (b != 0u);   // g > 0
    if (gpos && kp_) {
      const float tw = bf2f(qpB[i]) * bf2f(kcB[i]) - bf2f(qcB[i]) * bf2f(kpB[i]);
      accv += bf2f(mB[i]) * fabsf(tw);
    }
  }
  #pragma unroll
  for (int off = 1; off < 64; off <<= 1) accv += __shfl_xor(accv, off);
  if (ln == 0) craw[token] = accv * (1.0f / 1024.0f);
}

// ---------------- full token kernel (fallback path only) ----------------
__global__ __launch_bounds__(256) void token_kernel2(
    const float* __restrict__ x, const float* __restrict__ Wc,
    const unsigned short* __restrict__ qb, const unsigned short* __restrict__ kb,
    const unsigned short* __restrict__ gb, const unsigned short* __restrict__ mb,
    float* __restrict__ probs, float* __restrict__ craw)
{
  const int wv = threadIdx.x >> 6;
  const int ln = threadIdx.x & 63;
  const int token = blockIdx.x * 4 + wv;
  const int s = token & (SS - 1);
  const size_t rowo = (size_t)token * DD;

  const float4* x4 = (const float4*)(x + rowo);
  const float4* Wc4 = (const float4*)Wc;
  float4 xv[4];
  #pragma unroll
  for (int e = 0; e < 4; ++e) xv[e] = x4[e * 64 + ln];
  float pj[16];
  #pragma unroll
  for (int j = 0; j < 16; ++j) {
    float a = 0.f;
    #pragma unroll
    for (int e = 0; e < 4; ++e) {
      const float4 w = Wc4[j * 256 + e * 64 + ln];
      a += xv[e].x * w.x + xv[e].y * w.y + xv[e].z * w.z + xv[e].w * w.w;
    }
    pj[j] = a;
  }
  #pragma unroll
  for (int j = 0; j < 16; ++j) {
    #pragma unroll
    for (int off = 1; off < 64; off <<= 1) pj[j] += __shfl_xor(pj[j], off);
  }
  if (ln == 0) {
    float p[16];
    float mx = -3.4e38f;
    #pragma unroll
    for (int j = 0; j < 16; ++j) { p[j] = pj[j] * 10.0f; mx = fmaxf(mx, p[j]); }
    float se = 0.f;
    #pragma unroll
    for (int j = 0; j < 16; ++j) { p[j] = expf(p[j] - mx); se += p[j]; }
    const float inv = 1.0f / se;
    #pragma unroll
    for (int j = 0; j < 16; ++j) p[j] *= inv;
    unsigned int mk = 0;
    for (int it = 0; it < 4; ++it) {
      int bi = 0; float bv = -1.f;
      #pragma unroll
      for (int j = 0; j < 16; ++j)
        if (!((mk >> j) & 1u) && p[j] > bv) { bv = p[j]; bi = j; }
      mk |= 1u << bi;
    }
    float ssum = 0.f;
    #pragma unroll
    for (int j = 0; j < 16; ++j) if ((mk >> j) & 1u) ssum += p[j];
    const float rinv = 1.0f / fmaxf(ssum, 1e-8f);
    #pragma unroll
    for (int j = 0; j < 16; ++j)
      probs[(size_t)token * 16 + j] = ((mk >> j) & 1u) ? p[j] * rinv : 0.f;
  }

  if (s == 0) { if (ln == 0) craw[token] = 0.f; return; }

  unsigned short gbit[16];
  *(uint4*)&gbit[0] = *(const uint4*)(gb + rowo + ln * 16);
  *(uint4*)&gbit[8] = *(const uint4*)(gb + rowo + ln * 16 + 8);
  int ckey[16];
  float asum = 0.f;
  #pragma unroll
  for (int i = 0; i < 16; ++i) {
    const unsigned int b = gbit[i];
    ckey[i] = (b & 0x8000u) ? (int)(b ^ 0xFFFFu) : (int)(b | 0x8000u);
    asum += bf2f(b & 0x7FFFu);
  }
  #pragma unroll
  for (int off = 1; off < 64; off <<= 1) asum += __shfl_xor(asum, off);
  const float strength = tanhf(asum * (1.0f / 1024.0f));
  int kkv = (int)ceilf(strength * 256.0f);
  kkv = min(max(kkv, 1), 1024);

  int lo = 0, hi = 0xFFFF;
  while (lo < hi) {
    const int mid = (lo + hi + 1) >> 1;
    int c = 0;
    #pragma unroll
    for (int i = 0; i < 16; ++i) c += (ckey[i] >= mid);
    #pragma unroll
    for (int off = 1; off < 64; off <<= 1) c += __shfl_xor(c, off);
    if (c >= kkv) lo = mid; else hi = mid - 1;
  }
  const int T = lo;

  int cg = 0, myeq = 0;
  #pragma unroll
  for (int i = 0; i < 16; ++i) { cg += (ckey[i] > T); myeq += (ckey[i] == T); }
  #pragma unroll
  for (int off = 1; off < 64; off <<= 1) cg += __shfl_xor(cg, off);
  int incl = myeq;
  #pragma unroll
  for (int off = 1; off < 64; off <<= 1) {
    const int tt = __shfl_up(incl, off);
    if (ln >= off) incl += tt;
  }
  int ebase = incl - myeq;
  const int keep_eq = kkv - cg;

  unsigned short mB[16], qcB[16], kcB[16], qpB[16], kpB[16];
  *(uint4*)&mB[0]  = *(const uint4*)(mb + rowo + ln * 16);
  *(uint4*)&mB[8]  = *(const uint4*)(mb + rowo + ln * 16 + 8);
  *(uint4*)&qcB[0] = *(const uint4*)(qb + rowo + ln * 16);
  *(uint4*)&qcB[8] = *(const uint4*)(qb + rowo + ln * 16 + 8);
  *(uint4*)&kcB[0] = *(const uint4*)(kb + rowo + ln * 16);
  *(uint4*)&kcB[8] = *(const uint4*)(kb + rowo + ln * 16 + 8);
  *(uint4*)&qpB[0] = *(const uint4*)(qb + rowo - DD + ln * 16);
  *(uint4*)&qpB[8] = *(const uint4*)(qb + rowo - DD + ln * 16 + 8);
  *(uint4*)&kpB[0] = *(const uint4*)(kb + rowo - DD + ln * 16);
  *(uint4*)&kpB[8] = *(const uint4*)(kb + rowo - DD + ln * 16 + 8);

  float accv = 0.f;
  #pragma unroll
  for (int i = 0; i < 16; ++i) {
    const bool kp_ = (ckey[i] > T) || (ckey[i] == T && ebase < keep_eq);
    if (ckey[i] == T) ebase++;
    const unsigned int b = gbit[i];
    const bool gpos = (!(b & 0x8000u)) && (b != 0u);
    if (gpos && kp_) {
      const float tw = bf2f(qpB[i]) * bf2f(kcB[i]) - bf2f(qcB[i]) * bf2f(kpB[i]);
      accv += bf2f(mB[i]) * fabsf(tw);
    }
  }
  #pragma unroll
  for (int off = 1; off < 64; off <<= 1) accv += __shfl_xor(accv, off);
  if (ln == 0) craw[token] = accv * (1.0f / 1024.0f);
}

// ---------------- Phase 3a: quorum sigmoid + codebook shift score ----------------
__global__ __launch_bounds__(256) void quorum_kernel(
    const float* __restrict__ craw, const float* __restrict__ probs,
    float* __restrict__ quorum, float* __restrict__ cb)
{
  const int idx = blockIdx.x * 256 + threadIdx.x;
  const int s = idx & (SS - 1);
  const float c1 = craw[idx];
  const float c0 = (s > 0) ? craw[idx - 1] : 0.f;
  const float c2 = (s < SS - 1) ? craw[idx + 1] : 0.f;
  const float local = (c0 + c1 + c2) / 3.0f;
  quorum[idx] = 1.0f / (1.0f + expf((0.5f - local) * 10.0f));
  float sh = 0.f;
  if (s > 0) {
    #pragma unroll
    for (int j = 0; j < 16; ++j)
      sh += fabsf(probs[(size_t)idx * 16 + j] - probs[(size_t)(idx - 1) * 16 + j]);
  }
  cb[idx] = 0.5f * sh;
}

// ---------------- Phase 3b: per-batch budget top-2048 + final mix ----------------
__global__ __launch_bounds__(64) void final_kernel(
    const float* __restrict__ craw, const float* __restrict__ quorum,
    const float* __restrict__ cb, float* __restrict__ outp)
{
  const int b = blockIdx.x;
  const int ln = threadIdx.x;
  const size_t base = (size_t)b * SS;
  float qv[64]; unsigned int key[64];
  #pragma unroll
  for (int i = 0; i < 64; ++i) {
    qv[i] = quorum[base + ln * 64 + i];
    const unsigned int bb = __float_as_uint(qv[i]);
    key[i] = (bb & 0x80000000u) ? ~bb : (bb | 0x80000000u);
  }
  unsigned int lo = 0u, hi = 0xFFFFFFFFu;
  while (lo < hi) {
    const unsigned int mid = (unsigned int)(((unsigned long long)lo + hi + 1ull) >> 1);
    int c = 0;
    #pragma unroll
    for (int i = 0; i < 64; ++i) c += (key[i] >= mid);
    #pragma unroll
    for (int off = 1; off < 64; off <<= 1) c += __shfl_xor(c, off);
    if (c >= BUDGET) lo = mid; else hi = mid - 1;
  }
  const unsigned int T = lo;
  int cg = 0, myeq = 0;
  #pragma unroll
  for (int i = 0; i < 64; ++i) { cg += (key[i] > T); myeq += (key[i] == T); }
  #pragma unroll
  for (int off = 1; off < 64; off <<= 1) cg += __shfl_xor(cg, off);
  int scan = myeq;
  #pragma unroll
  for (int off = 1; off < 64; off <<= 1) {
    const int nsc = __shfl_up(scan, off);
    if (ln >= off) scan += nsc;
  }
  int ebase = scan - myeq;
  const int keep_eq = BUDGET - cg;
  #pragma unroll
  for (int i = 0; i < 64; ++i) {
    const size_t sidx = base + (size_t)ln * 64 + i;
    const bool kp_ = (key[i] > T) || (key[i] == T && ebase < keep_eq);
    if (key[i] == T) ebase++;
    const float q = kp_ ? qv[i] : 0.f;
    outp[sidx] = 0.7f * (craw[sidx] * (0.5f + 0.5f * q)) + 0.3f * cb[sidx];
  }
}

extern "C" void kernel_launch(void* const* d_in, const int* in_sizes, int n_in,
                              void* d_out, int out_size, void* d_ws, size_t ws_size,
                              hipStream_t stream)
{
  const float* x  = (const float*)d_in[0];
  const float* Wq = (const float*)d_in[1];
  const float* Wk = (const float*)d_in[2];
  const float* Wg = (const float*)d_in[3];
  const float* bg = (const float*)d_in[4];
  const float* Wm = (const float*)d_in[5];
  const float* bm = (const float*)d_in[6];
  const float* Wc = (const float*)d_in[7];
  float* outp = (float*)d_out;
  char* w = (char*)d_ws;

  const size_t SZ_BF = (size_t)MM * DD * 2;        // 32 MB per bf16 intermediate
  const size_t SMALL_OFF = 4 * SZ_BF;              // 134217728
  const size_t SZ_SMALL = 1048576 + 3 * 65536;     // probs + craw/quorum/cb

  unsigned short* qb = (unsigned short*)(w);
  unsigned short* kb = (unsigned short*)(w + SZ_BF);
  unsigned short* gb = (unsigned short*)(w + 2 * SZ_BF);
  unsigned short* mb = (unsigned short*)(w + 3 * SZ_BF);
  char* sm = w + SMALL_OFF;
  float* probs  = (float*)(sm);
  float* craw   = (float*)(sm + 1048576);
  float* quorum = (float*)(sm + 1048576 + 65536);
  float* cbuf   = (float*)(sm + 1048576 + 2 * 65536);

  const size_t need_mid = SMALL_OFF + SZ_SMALL + SZ_BF + (size_t)4 * 1048576 * 2;

  if (ws_size >= need_mid) {
    unsigned short* xb = (unsigned short*)(sm + SZ_SMALL);
    unsigned short* Wb = xb + (size_t)MM * DD;
    convert2_kernel<<<dim3(4096 + 2048), 256, 0, stream>>>(
        x, Wq, Wk, Wg, Wm, Wc, xb, Wb, probs);
    gemm256_kernel<<<dim3(NTOT / 256, MM / 256), 1024, 0, stream>>>(
        xb, Wb, bg, bm, qb, kb, gb, mb);
    token_kernel3<<<dim3(MM / 4), 256, 0, stream>>>(qb, kb, gb, mb, craw);
  } else {
    mfma_gemm_fb<<<dim3(NTOT / 128, MM / 128), 256, 0, stream>>>(
        x, Wq, Wk, Wg, Wm, bg, bm, qb, kb, gb, mb);
    token_kernel2<<<dim3(MM / 4), 256, 0, stream>>>(x, Wc, qb, kb, gb, mb, probs, craw);
  }
  quorum_kernel<<<dim3(MM / 256), 256, 0, stream>>>(craw, probs, quorum, cbuf);
  final_kernel<<<dim3(BB), 64, 0, stream>>>(craw, quorum, cbuf, outp);
}